// Round 6
// baseline (1365.407 us; speedup 1.0000x reference)
//
#include <hip/hip_runtime.h>

// Graph-transformer MHA layer. N=50000, E=1600000, IN_DIM=64, H=8, D=8.
// Outputs: h_out [N*64] then e_out [E*64], fp32, concatenated in d_out.
//
// R6: edge pass = 256-thread block / 64 edges; wave w owns output dims
// [16w,16w+16) (= heads 2w,2w+1), lane = edge. Each wave re-reads the e-row
// from global (L2-hit for waves 1-3). Scores staged in XOR-swizzled LDS tile,
// written out as full-line coalesced dwordx4 stores. Head gates exchanged via
// transposed LDS buffer; wave 0 issues cursor atomic EARLY (pos independent
// of g) and writes s_sorted after the single barrier.

// ---------------- node projection ----------------
__global__ __launch_bounds__(256)
void proj_kernel(const float* __restrict__ hsrc,
                 const float* __restrict__ Wq, const float* __restrict__ bq,
                 const float* __restrict__ Wk, const float* __restrict__ bk,
                 const float* __restrict__ Wv, const float* __restrict__ bv,
                 float* __restrict__ Q, float* __restrict__ K, float* __restrict__ V,
                 int n)
{
    const float* W;
    const float* b;
    float* out;
    if (blockIdx.y == 0)      { W = Wq; b = bq; out = Q; }
    else if (blockIdx.y == 1) { W = Wk; b = bk; out = K; }
    else                      { W = Wv; b = bv; out = V; }

    const int t    = threadIdx.x;
    const int lane = t & 63;
    const int w    = t >> 6;

    float wcol[64];
#pragma unroll
    for (int k = 0; k < 64; ++k) wcol[k] = W[k * 64 + lane];
    const float bias = b[lane];

    __shared__ float4 sh[16][16];
    const float4* __restrict__ h4 = (const float4*)hsrc;

    const int ngroups = (n + 15) >> 4;
    for (int g = blockIdx.x; g < ngroups; g += gridDim.x) {
        const int base = g << 4;
        {
            const int rs = t >> 4, c4 = t & 15;
            float4 v = make_float4(0.f, 0.f, 0.f, 0.f);
            if (base + rs < n) v = h4[(size_t)(base + rs) * 16 + c4];
            __syncthreads();
            sh[rs][c4] = v;
            __syncthreads();
        }
        float acc0 = bias, acc1 = bias, acc2 = bias, acc3 = bias;
#pragma unroll
        for (int k4 = 0; k4 < 16; ++k4) {
            const float w0 = wcol[k4 * 4 + 0], w1 = wcol[k4 * 4 + 1];
            const float w2 = wcol[k4 * 4 + 2], w3 = wcol[k4 * 4 + 3];
            const float4 a = sh[w * 4 + 0][k4];
            const float4 bb = sh[w * 4 + 1][k4];
            const float4 c = sh[w * 4 + 2][k4];
            const float4 d = sh[w * 4 + 3][k4];
            acc0 = fmaf(a.w,  w3, fmaf(a.z,  w2, fmaf(a.y,  w1, fmaf(a.x,  w0, acc0))));
            acc1 = fmaf(bb.w, w3, fmaf(bb.z, w2, fmaf(bb.y, w1, fmaf(bb.x, w0, acc1))));
            acc2 = fmaf(c.w,  w3, fmaf(c.z,  w2, fmaf(c.y,  w1, fmaf(c.x,  w0, acc2))));
            acc3 = fmaf(d.w,  w3, fmaf(d.z,  w2, fmaf(d.y,  w1, fmaf(d.x,  w0, acc3))));
        }
        const int n0 = base + w * 4;
        if (n0 + 0 < n) out[(size_t)(n0 + 0) * 64 + lane] = acc0;
        if (n0 + 1 < n) out[(size_t)(n0 + 1) * 64 + lane] = acc1;
        if (n0 + 2 < n) out[(size_t)(n0 + 2) * 64 + lane] = acc2;
        if (n0 + 3 < n) out[(size_t)(n0 + 3) * 64 + lane] = acc3;
    }
}

// ---------------- dst histogram ----------------
__global__ __launch_bounds__(256)
void hist_kernel(const int* __restrict__ dst, int* __restrict__ counts, int E)
{
    int i = blockIdx.x * 256 + threadIdx.x;
    const int stride = gridDim.x * 256;
    for (; i < E; i += stride) atomicAdd(&counts[dst[i]], 1);
}

// ---------------- exclusive scan over counts (single block, 1024 thr) ----------------
__global__ __launch_bounds__(1024)
void scan_kernel(const int* __restrict__ counts, int* __restrict__ offsets,
                 int* __restrict__ cursor, int n, int E)
{
    __shared__ int wsum[16];
    const int t = threadIdx.x;
    const int lane = t & 63;
    const int w = t >> 6;
    int carry = 0;
    for (int base = 0; base < n; base += 1024) {
        const int i = base + t;
        const int v = (i < n) ? counts[i] : 0;
        int x = v;
#pragma unroll
        for (int d = 1; d < 64; d <<= 1) {
            int y = __shfl_up(x, d);
            if (lane >= d) x += y;
        }
        if (lane == 63) wsum[w] = x;
        __syncthreads();
        if (w == 0 && lane < 16) {
            int s = wsum[lane];
#pragma unroll
            for (int d = 1; d < 16; d <<= 1) {
                int y = __shfl_up(s, d);
                if (lane >= d) s += y;
            }
            wsum[lane] = s;
        }
        __syncthreads();
        const int woff = (w == 0) ? 0 : wsum[w - 1];
        const int excl = carry + woff + (x - v);
        if (i < n) { offsets[i] = excl; cursor[i] = excl; }
        carry += wsum[15];
        __syncthreads();
    }
    if (t == 0) offsets[n] = E;
}

// 16 FMAs of uniform We values into 4 named float4 accumulators
#define FMA16(s, W) do { \
    const float* _w = (W); \
    accA.x = fmaf((s), _w[0],  accA.x); accA.y = fmaf((s), _w[1],  accA.y); \
    accA.z = fmaf((s), _w[2],  accA.z); accA.w = fmaf((s), _w[3],  accA.w); \
    accB.x = fmaf((s), _w[4],  accB.x); accB.y = fmaf((s), _w[5],  accB.y); \
    accB.z = fmaf((s), _w[6],  accB.z); accB.w = fmaf((s), _w[7],  accB.w); \
    accC.x = fmaf((s), _w[8],  accC.x); accC.y = fmaf((s), _w[9],  accC.y); \
    accC.z = fmaf((s), _w[10], accC.z); accC.w = fmaf((s), _w[11], accC.w); \
    accD.x = fmaf((s), _w[12], accD.x); accD.y = fmaf((s), _w[13], accD.y); \
    accD.z = fmaf((s), _w[14], accD.z); accD.w = fmaf((s), _w[15], accD.w); \
} while (0)

#define K4X(EV, kb) \
    FMA16((EV).x, Wc + (kb + 0) * 64); \
    FMA16((EV).y, Wc + (kb + 1) * 64); \
    FMA16((EV).z, Wc + (kb + 2) * 64); \
    FMA16((EV).w, Wc + (kb + 3) * 64);

// ---------------- edge kernel v6: 4 waves split j-dim; lane = edge ----------------
__global__ __launch_bounds__(256)
void edge_kernel(const float* __restrict__ e,
                 const float* __restrict__ We, const float* __restrict__ be,
                 const int* __restrict__ src, const int* __restrict__ dst,
                 const float* __restrict__ Q, const float* __restrict__ K,
                 float* __restrict__ e_out,
                 float* __restrict__ s_sorted, int* __restrict__ src_sorted,
                 int* __restrict__ cursor, int E)
{
    __shared__ float4 tile4[64 * 16];   // 16 KB score tile, cols XOR-swizzled
    __shared__ float gbufT[8][64];      // transposed gate exchange (conflict-free b32)

    const int t    = threadIdx.x;
    const int lane = t & 63;            // edge within tile
    const int w    = t >> 6;            // chunk: output dims [16w,16w+16) = heads 2w,2w+1
    const int base = blockIdx.x * 64;
    if (base >= E) return;

    const float inv_sqrt_d = 0.35355339059327373f;  // 1/sqrt(8)

    const int eid   = base + lane;
    const bool valid = eid < E;
    const int eidc  = valid ? eid : (E - 1);
    const int lx    = lane & 15;

    const int s_ = src[eidc];
    const int d_ = dst[eidc];

    // wave 0: claim slot early (pos does not depend on the gates)
    int pos = 0;
    if (w == 0 && valid) {
        pos = atomicAdd(&cursor[d_], 1);
        src_sorted[pos] = s_;
    }

    // K/Q slices for this wave's 2 heads (gathers issued before the FMA wall)
    const float4* __restrict__ krow = (const float4*)(K + (size_t)s_ * 64 + w * 16);
    const float4* __restrict__ qrow = (const float4*)(Q + (size_t)d_ * 64 + w * 16);
    const float4 kv0 = krow[0], kv1 = krow[1], kv2 = krow[2], kv3 = krow[3];
    const float4 qv0 = qrow[0], qv1 = qrow[1], qv2 = qrow[2], qv3 = qrow[3];

    // e row -> 16 named float4s (waves 1-3 hit L2 on the re-read)
    const float4* __restrict__ erow = (const float4*)(e + (size_t)eidc * 64);
    const float4 ev0 = erow[0],  ev1 = erow[1],  ev2 = erow[2],  ev3 = erow[3];
    const float4 ev4 = erow[4],  ev5 = erow[5],  ev6 = erow[6],  ev7 = erow[7];
    const float4 ev8 = erow[8],  ev9 = erow[9],  ev10 = erow[10], ev11 = erow[11];
    const float4 ev12 = erow[12], ev13 = erow[13], ev14 = erow[14], ev15 = erow[15];

    // projection for this wave's 16 output dims
    const float* Wc = We + w * 16;
    const float4* be4 = (const float4*)(be + w * 16);
    float4 accA = be4[0], accB = be4[1], accC = be4[2], accD = be4[3];
    K4X(ev0, 0)   K4X(ev1, 4)   K4X(ev2, 8)   K4X(ev3, 12)
    K4X(ev4, 16)  K4X(ev5, 20)  K4X(ev6, 24)  K4X(ev7, 28)
    K4X(ev8, 32)  K4X(ev9, 36)  K4X(ev10, 40) K4X(ev11, 44)
    K4X(ev12, 48) K4X(ev13, 52) K4X(ev14, 56) K4X(ev15, 60)

    // scores
    float4 s0, s1, s2, s3;
    s0.x = kv0.x*qv0.x*inv_sqrt_d*accA.x; s0.y = kv0.y*qv0.y*inv_sqrt_d*accA.y;
    s0.z = kv0.z*qv0.z*inv_sqrt_d*accA.z; s0.w = kv0.w*qv0.w*inv_sqrt_d*accA.w;
    s1.x = kv1.x*qv1.x*inv_sqrt_d*accB.x; s1.y = kv1.y*qv1.y*inv_sqrt_d*accB.y;
    s1.z = kv1.z*qv1.z*inv_sqrt_d*accB.z; s1.w = kv1.w*qv1.w*inv_sqrt_d*accB.w;
    s2.x = kv2.x*qv2.x*inv_sqrt_d*accC.x; s2.y = kv2.y*qv2.y*inv_sqrt_d*accC.y;
    s2.z = kv2.z*qv2.z*inv_sqrt_d*accC.z; s2.w = kv2.w*qv2.w*inv_sqrt_d*accC.w;
    s3.x = kv3.x*qv3.x*inv_sqrt_d*accD.x; s3.y = kv3.y*qv3.y*inv_sqrt_d*accD.y;
    s3.z = kv3.z*qv3.z*inv_sqrt_d*accD.z; s3.w = kv3.w*qv3.w*inv_sqrt_d*accD.w;

    // stage scores (swizzled) + gates
    tile4[lane * 16 + ((w * 4 + 0) ^ lx)] = s0;
    tile4[lane * 16 + ((w * 4 + 1) ^ lx)] = s1;
    tile4[lane * 16 + ((w * 4 + 2) ^ lx)] = s2;
    tile4[lane * 16 + ((w * 4 + 3) ^ lx)] = s3;

    const float hsL = ((s0.x+s0.y)+(s0.z+s0.w)) + ((s1.x+s1.y)+(s1.z+s1.w));
    const float hsH = ((s2.x+s2.y)+(s2.z+s2.w)) + ((s3.x+s3.y)+(s3.z+s3.w));
    gbufT[2 * w + 0][lane] = expf(fminf(fmaxf(hsL, -5.f), 5.f));
    gbufT[2 * w + 1][lane] = expf(fminf(fmaxf(hsH, -5.f), 5.f));

    __syncthreads();

    // cooperative transposed write-out: 4 x (256 threads x 16B) full-line stores
    float4* __restrict__ out4 = (float4*)(e_out + (size_t)base * 64);
    const size_t limit4 = (size_t)E * 16;
    const size_t base4  = (size_t)base * 16;
#pragma unroll
    for (int i = 0; i < 4; ++i) {
        const int f = i * 256 + t;            // float4 index within the 16KB tile
        const int r = f >> 4;                 // tile row (edge)
        const int m = f & 15;                 // tile col (float4 units)
        const float4 v = tile4[r * 16 + (m ^ (r & 15))];
        if (base4 + (size_t)f < limit4) out4[f] = v;
    }

    // wave 0 writes the 8 gates for its edge
    if (w == 0 && valid) {
        float4* srow = (float4*)(s_sorted + (size_t)pos * 8);
        srow[0] = make_float4(gbufT[0][lane], gbufT[1][lane], gbufT[2][lane], gbufT[3][lane]);
        srow[1] = make_float4(gbufT[4][lane], gbufT[5][lane], gbufT[6][lane], gbufT[7][lane]);
    }
}

// ---------------- aggregation: one wave per node, no atomics ----------------
__global__ __launch_bounds__(256)
void aggregate_kernel(const int* __restrict__ offsets,
                      const int* __restrict__ src_sorted,
                      const float* __restrict__ s_sorted,
                      const float* __restrict__ V,
                      float* __restrict__ hout, int n)
{
    const int w = (blockIdx.x * 256 + threadIdx.x) >> 6;
    const int lane = threadIdx.x & 63;
    if (w >= n) return;
    const int o0 = offsets[w], o1 = offsets[w + 1];
    const int head = lane >> 3;
    float acc = 0.f, zacc = 0.f;
    int j = o0;
    for (; j + 4 <= o1; j += 4) {
        const int sv0 = src_sorted[j + 0];
        const int sv1 = src_sorted[j + 1];
        const int sv2 = src_sorted[j + 2];
        const int sv3 = src_sorted[j + 3];
        const float s0 = s_sorted[(size_t)(j + 0) * 8 + head];
        const float s1 = s_sorted[(size_t)(j + 1) * 8 + head];
        const float s2 = s_sorted[(size_t)(j + 2) * 8 + head];
        const float s3 = s_sorted[(size_t)(j + 3) * 8 + head];
        const float v0 = V[(size_t)sv0 * 64 + lane];
        const float v1 = V[(size_t)sv1 * 64 + lane];
        const float v2 = V[(size_t)sv2 * 64 + lane];
        const float v3 = V[(size_t)sv3 * 64 + lane];
        acc = fmaf(v0, s0, acc);
        acc = fmaf(v1, s1, acc);
        acc = fmaf(v2, s2, acc);
        acc = fmaf(v3, s3, acc);
        zacc += (s0 + s1) + (s2 + s3);
    }
    for (; j < o1; ++j) {
        const int sv = src_sorted[j];
        const float s = s_sorted[(size_t)j * 8 + head];
        acc = fmaf(V[(size_t)sv * 64 + lane], s, acc);
        zacc += s;
    }
    hout[(size_t)w * 64 + lane] = acc / (zacc + 1e-6f);
}

extern "C" void kernel_launch(void* const* d_in, const int* in_sizes, int n_in,
                              void* d_out, int out_size, void* d_ws, size_t ws_size,
                              hipStream_t stream)
{
    const float* h  = (const float*)d_in[0];
    const float* e  = (const float*)d_in[1];
    const float* Wq = (const float*)d_in[2];
    const float* bq = (const float*)d_in[3];
    const float* Wk = (const float*)d_in[4];
    const float* bk = (const float*)d_in[5];
    const float* Wv = (const float*)d_in[6];
    const float* bv = (const float*)d_in[7];
    const float* We = (const float*)d_in[8];
    const float* be = (const float*)d_in[9];
    const int* src  = (const int*)d_in[10];
    const int* dst  = (const int*)d_in[11];

    const int N = in_sizes[0] / 64;
    const int E = in_sizes[1] / 64;

    float* hout  = (float*)d_out;                    // [N*64]
    float* e_out = (float*)d_out + (size_t)N * 64;   // [E*64]

    // workspace layout
    char* ws = (char*)d_ws;
    float* Q = (float*)ws;                 ws += (size_t)N * 64 * sizeof(float);
    float* K = (float*)ws;                 ws += (size_t)N * 64 * sizeof(float);
    float* V = (float*)ws;                 ws += (size_t)N * 64 * sizeof(float);
    float* s_sorted = (float*)ws;          ws += (size_t)E * 8 * sizeof(float);
    int* src_sorted = (int*)ws;            ws += (size_t)E * sizeof(int);
    int* counts  = (int*)ws;               ws += (size_t)N * sizeof(int);
    int* offsets = (int*)ws;               ws += (size_t)(N + 1) * sizeof(int);
    int* cursor  = (int*)ws;               ws += (size_t)N * sizeof(int);

    hipMemsetAsync(counts, 0, (size_t)N * sizeof(int), stream);

    // 1) Q,K,V projections
    proj_kernel<<<dim3(512, 3), dim3(256), 0, stream>>>(
        h, Wq, bq, Wk, bk, Wv, bv, Q, K, V, N);

    // 2) dst histogram
    hist_kernel<<<dim3(2048), dim3(256), 0, stream>>>(dst, counts, E);

    // 3) exclusive scan -> offsets, cursor
    scan_kernel<<<dim3(1), dim3(1024), 0, stream>>>(counts, offsets, cursor, N, E);

    // 4) edge pass: 256-thread block per 64-edge tile, waves split j-dim
    const int ntiles = (E + 63) >> 6;               // 25000 tiles
    edge_kernel<<<dim3(ntiles), dim3(256), 0, stream>>>(
        e, We, be, src, dst, Q, K, e_out, s_sorted, src_sorted, cursor, E);

    // 5) aggregate per node (one wave each)
    const int ablocks = (N * 64 + 255) / 256;
    aggregate_kernel<<<dim3(ablocks), dim3(256), 0, stream>>>(
        offsets, src_sorted, s_sorted, V, hout, N);
}

// Round 7
// 826.359 us; speedup vs baseline: 1.6523x; 1.6523x over previous
//
#include <hip/hip_runtime.h>

// Graph-transformer MHA layer. N=50000, E=1600000, IN_DIM=64, H=8, D=8.
// Outputs: h_out [N*64] then e_out [E*64], fp32, concatenated in d_out.
//
// R7 = R6 + readfirstlane fix: the per-wave chunk index wu is forced into an
// SGPR so We/be accesses are provably wave-uniform -> s_load (scalar pipe).
// R6 broke this (w = tid>>6 is per-wave-uniform but the compiler can't prove
// it) and every We read became a vector load: SGPR 112->48, VALUBusy 10%,
// 2x regression. HK technique: readfirstlane-hoist uniform bases to SGPR.

// ---------------- node projection ----------------
__global__ __launch_bounds__(256)
void proj_kernel(const float* __restrict__ hsrc,
                 const float* __restrict__ Wq, const float* __restrict__ bq,
                 const float* __restrict__ Wk, const float* __restrict__ bk,
                 const float* __restrict__ Wv, const float* __restrict__ bv,
                 float* __restrict__ Q, float* __restrict__ K, float* __restrict__ V,
                 int n)
{
    const float* W;
    const float* b;
    float* out;
    if (blockIdx.y == 0)      { W = Wq; b = bq; out = Q; }
    else if (blockIdx.y == 1) { W = Wk; b = bk; out = K; }
    else                      { W = Wv; b = bv; out = V; }

    const int t    = threadIdx.x;
    const int lane = t & 63;
    const int w    = t >> 6;

    float wcol[64];
#pragma unroll
    for (int k = 0; k < 64; ++k) wcol[k] = W[k * 64 + lane];
    const float bias = b[lane];

    __shared__ float4 sh[16][16];
    const float4* __restrict__ h4 = (const float4*)hsrc;

    const int ngroups = (n + 15) >> 4;
    for (int g = blockIdx.x; g < ngroups; g += gridDim.x) {
        const int base = g << 4;
        {
            const int rs = t >> 4, c4 = t & 15;
            float4 v = make_float4(0.f, 0.f, 0.f, 0.f);
            if (base + rs < n) v = h4[(size_t)(base + rs) * 16 + c4];
            __syncthreads();
            sh[rs][c4] = v;
            __syncthreads();
        }
        float acc0 = bias, acc1 = bias, acc2 = bias, acc3 = bias;
#pragma unroll
        for (int k4 = 0; k4 < 16; ++k4) {
            const float w0 = wcol[k4 * 4 + 0], w1 = wcol[k4 * 4 + 1];
            const float w2 = wcol[k4 * 4 + 2], w3 = wcol[k4 * 4 + 3];
            const float4 a = sh[w * 4 + 0][k4];
            const float4 bb = sh[w * 4 + 1][k4];
            const float4 c = sh[w * 4 + 2][k4];
            const float4 d = sh[w * 4 + 3][k4];
            acc0 = fmaf(a.w,  w3, fmaf(a.z,  w2, fmaf(a.y,  w1, fmaf(a.x,  w0, acc0))));
            acc1 = fmaf(bb.w, w3, fmaf(bb.z, w2, fmaf(bb.y, w1, fmaf(bb.x, w0, acc1))));
            acc2 = fmaf(c.w,  w3, fmaf(c.z,  w2, fmaf(c.y,  w1, fmaf(c.x,  w0, acc2))));
            acc3 = fmaf(d.w,  w3, fmaf(d.z,  w2, fmaf(d.y,  w1, fmaf(d.x,  w0, acc3))));
        }
        const int n0 = base + w * 4;
        if (n0 + 0 < n) out[(size_t)(n0 + 0) * 64 + lane] = acc0;
        if (n0 + 1 < n) out[(size_t)(n0 + 1) * 64 + lane] = acc1;
        if (n0 + 2 < n) out[(size_t)(n0 + 2) * 64 + lane] = acc2;
        if (n0 + 3 < n) out[(size_t)(n0 + 3) * 64 + lane] = acc3;
    }
}

// ---------------- dst histogram ----------------
__global__ __launch_bounds__(256)
void hist_kernel(const int* __restrict__ dst, int* __restrict__ counts, int E)
{
    int i = blockIdx.x * 256 + threadIdx.x;
    const int stride = gridDim.x * 256;
    for (; i < E; i += stride) atomicAdd(&counts[dst[i]], 1);
}

// ---------------- exclusive scan over counts (single block, 1024 thr) ----------------
__global__ __launch_bounds__(1024)
void scan_kernel(const int* __restrict__ counts, int* __restrict__ offsets,
                 int* __restrict__ cursor, int n, int E)
{
    __shared__ int wsum[16];
    const int t = threadIdx.x;
    const int lane = t & 63;
    const int w = t >> 6;
    int carry = 0;
    for (int base = 0; base < n; base += 1024) {
        const int i = base + t;
        const int v = (i < n) ? counts[i] : 0;
        int x = v;
#pragma unroll
        for (int d = 1; d < 64; d <<= 1) {
            int y = __shfl_up(x, d);
            if (lane >= d) x += y;
        }
        if (lane == 63) wsum[w] = x;
        __syncthreads();
        if (w == 0 && lane < 16) {
            int s = wsum[lane];
#pragma unroll
            for (int d = 1; d < 16; d <<= 1) {
                int y = __shfl_up(s, d);
                if (lane >= d) s += y;
            }
            wsum[lane] = s;
        }
        __syncthreads();
        const int woff = (w == 0) ? 0 : wsum[w - 1];
        const int excl = carry + woff + (x - v);
        if (i < n) { offsets[i] = excl; cursor[i] = excl; }
        carry += wsum[15];
        __syncthreads();
    }
    if (t == 0) offsets[n] = E;
}

// 16 FMAs of uniform We values into 4 named float4 accumulators
#define FMA16(s, W) do { \
    const float* _w = (W); \
    accA.x = fmaf((s), _w[0],  accA.x); accA.y = fmaf((s), _w[1],  accA.y); \
    accA.z = fmaf((s), _w[2],  accA.z); accA.w = fmaf((s), _w[3],  accA.w); \
    accB.x = fmaf((s), _w[4],  accB.x); accB.y = fmaf((s), _w[5],  accB.y); \
    accB.z = fmaf((s), _w[6],  accB.z); accB.w = fmaf((s), _w[7],  accB.w); \
    accC.x = fmaf((s), _w[8],  accC.x); accC.y = fmaf((s), _w[9],  accC.y); \
    accC.z = fmaf((s), _w[10], accC.z); accC.w = fmaf((s), _w[11], accC.w); \
    accD.x = fmaf((s), _w[12], accD.x); accD.y = fmaf((s), _w[13], accD.y); \
    accD.z = fmaf((s), _w[14], accD.z); accD.w = fmaf((s), _w[15], accD.w); \
} while (0)

#define K4X(EV, kb) \
    FMA16((EV).x, Wc + (kb + 0) * 64); \
    FMA16((EV).y, Wc + (kb + 1) * 64); \
    FMA16((EV).z, Wc + (kb + 2) * 64); \
    FMA16((EV).w, Wc + (kb + 3) * 64);

// ---------------- edge kernel v7: 4 waves split j-dim; lane = edge ----------------
__global__ __launch_bounds__(256)
void edge_kernel(const float* __restrict__ e,
                 const float* __restrict__ We, const float* __restrict__ be,
                 const int* __restrict__ src, const int* __restrict__ dst,
                 const float* __restrict__ Q, const float* __restrict__ K,
                 float* __restrict__ e_out,
                 float* __restrict__ s_sorted, int* __restrict__ src_sorted,
                 int* __restrict__ cursor, int E)
{
    __shared__ float4 tile4[64 * 16];   // 16 KB score tile, cols XOR-swizzled
    __shared__ float gbufT[8][64];      // transposed gate exchange (conflict-free b32)

    const int t    = threadIdx.x;
    const int lane = t & 63;            // edge within tile
    // wave's chunk index, FORCED into an SGPR so We/be accesses scalarize
    const int wu   = __builtin_amdgcn_readfirstlane(t >> 6);
    const int base = blockIdx.x * 64;
    if (base >= E) return;

    const float inv_sqrt_d = 0.35355339059327373f;  // 1/sqrt(8)

    const int eid   = base + lane;
    const bool valid = eid < E;
    const int eidc  = valid ? eid : (E - 1);
    const int lx    = lane & 15;

    const int s_ = src[eidc];
    const int d_ = dst[eidc];

    // wave 0: claim slot early (pos does not depend on the gates)
    int pos = 0;
    if (wu == 0 && valid) {
        pos = atomicAdd(&cursor[d_], 1);
        src_sorted[pos] = s_;
    }

    // K/Q slices for this wave's 2 heads (gathers issued before the FMA wall)
    const float4* __restrict__ krow = (const float4*)(K + (size_t)s_ * 64 + wu * 16);
    const float4* __restrict__ qrow = (const float4*)(Q + (size_t)d_ * 64 + wu * 16);
    const float4 kv0 = krow[0], kv1 = krow[1], kv2 = krow[2], kv3 = krow[3];
    const float4 qv0 = qrow[0], qv1 = qrow[1], qv2 = qrow[2], qv3 = qrow[3];

    // e row -> 16 named float4s (waves 1-3 hit L2 on the re-read)
    const float4* __restrict__ erow = (const float4*)(e + (size_t)eidc * 64);
    const float4 ev0 = erow[0],  ev1 = erow[1],  ev2 = erow[2],  ev3 = erow[3];
    const float4 ev4 = erow[4],  ev5 = erow[5],  ev6 = erow[6],  ev7 = erow[7];
    const float4 ev8 = erow[8],  ev9 = erow[9],  ev10 = erow[10], ev11 = erow[11];
    const float4 ev12 = erow[12], ev13 = erow[13], ev14 = erow[14], ev15 = erow[15];

    // projection for this wave's 16 output dims (Wc/be4 are SGPR-based -> s_load)
    const float* Wc = We + wu * 16;
    const float4* be4 = (const float4*)(be + wu * 16);
    float4 accA = be4[0], accB = be4[1], accC = be4[2], accD = be4[3];
    K4X(ev0, 0)   K4X(ev1, 4)   K4X(ev2, 8)   K4X(ev3, 12)
    K4X(ev4, 16)  K4X(ev5, 20)  K4X(ev6, 24)  K4X(ev7, 28)
    K4X(ev8, 32)  K4X(ev9, 36)  K4X(ev10, 40) K4X(ev11, 44)
    K4X(ev12, 48) K4X(ev13, 52) K4X(ev14, 56) K4X(ev15, 60)

    // scores
    float4 s0, s1, s2, s3;
    s0.x = kv0.x*qv0.x*inv_sqrt_d*accA.x; s0.y = kv0.y*qv0.y*inv_sqrt_d*accA.y;
    s0.z = kv0.z*qv0.z*inv_sqrt_d*accA.z; s0.w = kv0.w*qv0.w*inv_sqrt_d*accA.w;
    s1.x = kv1.x*qv1.x*inv_sqrt_d*accB.x; s1.y = kv1.y*qv1.y*inv_sqrt_d*accB.y;
    s1.z = kv1.z*qv1.z*inv_sqrt_d*accB.z; s1.w = kv1.w*qv1.w*inv_sqrt_d*accB.w;
    s2.x = kv2.x*qv2.x*inv_sqrt_d*accC.x; s2.y = kv2.y*qv2.y*inv_sqrt_d*accC.y;
    s2.z = kv2.z*qv2.z*inv_sqrt_d*accC.z; s2.w = kv2.w*qv2.w*inv_sqrt_d*accC.w;
    s3.x = kv3.x*qv3.x*inv_sqrt_d*accD.x; s3.y = kv3.y*qv3.y*inv_sqrt_d*accD.y;
    s3.z = kv3.z*qv3.z*inv_sqrt_d*accD.z; s3.w = kv3.w*qv3.w*inv_sqrt_d*accD.w;

    // stage scores (swizzled) + gates
    tile4[lane * 16 + ((wu * 4 + 0) ^ lx)] = s0;
    tile4[lane * 16 + ((wu * 4 + 1) ^ lx)] = s1;
    tile4[lane * 16 + ((wu * 4 + 2) ^ lx)] = s2;
    tile4[lane * 16 + ((wu * 4 + 3) ^ lx)] = s3;

    const float hsL = ((s0.x+s0.y)+(s0.z+s0.w)) + ((s1.x+s1.y)+(s1.z+s1.w));
    const float hsH = ((s2.x+s2.y)+(s2.z+s2.w)) + ((s3.x+s3.y)+(s3.z+s3.w));
    gbufT[2 * wu + 0][lane] = expf(fminf(fmaxf(hsL, -5.f), 5.f));
    gbufT[2 * wu + 1][lane] = expf(fminf(fmaxf(hsH, -5.f), 5.f));

    __syncthreads();

    // cooperative transposed write-out: 4 x (256 threads x 16B) full-line stores
    float4* __restrict__ out4 = (float4*)(e_out + (size_t)base * 64);
    const size_t limit4 = (size_t)E * 16;
    const size_t base4  = (size_t)base * 16;
#pragma unroll
    for (int i = 0; i < 4; ++i) {
        const int f = i * 256 + t;            // float4 index within the 16KB tile
        const int r = f >> 4;                 // tile row (edge)
        const int m = f & 15;                 // tile col (float4 units)
        const float4 v = tile4[r * 16 + (m ^ (r & 15))];
        if (base4 + (size_t)f < limit4) out4[f] = v;
    }

    // wave 0 writes the 8 gates for its edge
    if (wu == 0 && valid) {
        float4* srow = (float4*)(s_sorted + (size_t)pos * 8);
        srow[0] = make_float4(gbufT[0][lane], gbufT[1][lane], gbufT[2][lane], gbufT[3][lane]);
        srow[1] = make_float4(gbufT[4][lane], gbufT[5][lane], gbufT[6][lane], gbufT[7][lane]);
    }
}

// ---------------- aggregation: one wave per node, no atomics ----------------
__global__ __launch_bounds__(256)
void aggregate_kernel(const int* __restrict__ offsets,
                      const int* __restrict__ src_sorted,
                      const float* __restrict__ s_sorted,
                      const float* __restrict__ V,
                      float* __restrict__ hout, int n)
{
    const int w = (blockIdx.x * 256 + threadIdx.x) >> 6;
    const int lane = threadIdx.x & 63;
    if (w >= n) return;
    const int o0 = offsets[w], o1 = offsets[w + 1];
    const int head = lane >> 3;
    float acc = 0.f, zacc = 0.f;
    int j = o0;
    for (; j + 4 <= o1; j += 4) {
        const int sv0 = src_sorted[j + 0];
        const int sv1 = src_sorted[j + 1];
        const int sv2 = src_sorted[j + 2];
        const int sv3 = src_sorted[j + 3];
        const float s0 = s_sorted[(size_t)(j + 0) * 8 + head];
        const float s1 = s_sorted[(size_t)(j + 1) * 8 + head];
        const float s2 = s_sorted[(size_t)(j + 2) * 8 + head];
        const float s3 = s_sorted[(size_t)(j + 3) * 8 + head];
        const float v0 = V[(size_t)sv0 * 64 + lane];
        const float v1 = V[(size_t)sv1 * 64 + lane];
        const float v2 = V[(size_t)sv2 * 64 + lane];
        const float v3 = V[(size_t)sv3 * 64 + lane];
        acc = fmaf(v0, s0, acc);
        acc = fmaf(v1, s1, acc);
        acc = fmaf(v2, s2, acc);
        acc = fmaf(v3, s3, acc);
        zacc += (s0 + s1) + (s2 + s3);
    }
    for (; j < o1; ++j) {
        const int sv = src_sorted[j];
        const float s = s_sorted[(size_t)j * 8 + head];
        acc = fmaf(V[(size_t)sv * 64 + lane], s, acc);
        zacc += s;
    }
    hout[(size_t)w * 64 + lane] = acc / (zacc + 1e-6f);
}

extern "C" void kernel_launch(void* const* d_in, const int* in_sizes, int n_in,
                              void* d_out, int out_size, void* d_ws, size_t ws_size,
                              hipStream_t stream)
{
    const float* h  = (const float*)d_in[0];
    const float* e  = (const float*)d_in[1];
    const float* Wq = (const float*)d_in[2];
    const float* bq = (const float*)d_in[3];
    const float* Wk = (const float*)d_in[4];
    const float* bk = (const float*)d_in[5];
    const float* Wv = (const float*)d_in[6];
    const float* bv = (const float*)d_in[7];
    const float* We = (const float*)d_in[8];
    const float* be = (const float*)d_in[9];
    const int* src  = (const int*)d_in[10];
    const int* dst  = (const int*)d_in[11];

    const int N = in_sizes[0] / 64;
    const int E = in_sizes[1] / 64;

    float* hout  = (float*)d_out;                    // [N*64]
    float* e_out = (float*)d_out + (size_t)N * 64;   // [E*64]

    // workspace layout
    char* ws = (char*)d_ws;
    float* Q = (float*)ws;                 ws += (size_t)N * 64 * sizeof(float);
    float* K = (float*)ws;                 ws += (size_t)N * 64 * sizeof(float);
    float* V = (float*)ws;                 ws += (size_t)N * 64 * sizeof(float);
    float* s_sorted = (float*)ws;          ws += (size_t)E * 8 * sizeof(float);
    int* src_sorted = (int*)ws;            ws += (size_t)E * sizeof(int);
    int* counts  = (int*)ws;               ws += (size_t)N * sizeof(int);
    int* offsets = (int*)ws;               ws += (size_t)(N + 1) * sizeof(int);
    int* cursor  = (int*)ws;               ws += (size_t)N * sizeof(int);

    hipMemsetAsync(counts, 0, (size_t)N * sizeof(int), stream);

    // 1) Q,K,V projections
    proj_kernel<<<dim3(512, 3), dim3(256), 0, stream>>>(
        h, Wq, bq, Wk, bk, Wv, bv, Q, K, V, N);

    // 2) dst histogram
    hist_kernel<<<dim3(2048), dim3(256), 0, stream>>>(dst, counts, E);

    // 3) exclusive scan -> offsets, cursor
    scan_kernel<<<dim3(1), dim3(1024), 0, stream>>>(counts, offsets, cursor, N, E);

    // 4) edge pass: 256-thread block per 64-edge tile, waves split j-dim
    const int ntiles = (E + 63) >> 6;               // 25000 tiles
    edge_kernel<<<dim3(ntiles), dim3(256), 0, stream>>>(
        e, We, be, src, dst, Q, K, e_out, s_sorted, src_sorted, cursor, E);

    // 5) aggregate per node (one wave each)
    const int ablocks = (N * 64 + 255) / 256;
    aggregate_kernel<<<dim3(ablocks), dim3(256), 0, stream>>>(
        offsets, src_sorted, s_sorted, V, hout, N);
}

// Round 8
// 611.912 us; speedup vs baseline: 2.2314x; 1.3505x over previous
//
#include <hip/hip_runtime.h>

// Graph-transformer MHA layer. N=50000, E=1600000, IN_DIM=64, H=8, D=8.
// Outputs: h_out [N*64] then e_out [E*64], fp32, concatenated in d_out.
//
// R8: edge pass uses MFMA. Per 64-edge tile (one wave, no barriers):
//   P = e_tile @ We  computed as  D[j][edge] = We^T (A) x e^T (B), 16x
//   v_mfma_f32_32x32x16_bf16 (4 D-tiles x 4 K-slices). We^T is held
//   PERMANENTLY in 32 VGPRs as bf16 A-fragments -> no s_load-gated FMA chain
//   (the R4/R5/R7 ~600us plateau: 64x {s_load We chunk -> lgkm wait -> 16 FMA}).
//   D cols = edge = lane&31 -> kv/qv gathers stay contiguous 16B; head sums are
//   per-lane + one shfl_xor(32). Scores exit via XOR-swizzled LDS transpose
//   (full-line coalesced stores). bf16 error ~0.02 << 0.28 threshold.

using short8 = __attribute__((ext_vector_type(8))) short;
using f32x16 = __attribute__((ext_vector_type(16))) float;

__device__ __forceinline__ short f2bf(float f) {
    unsigned u = __builtin_bit_cast(unsigned, f);
    u += 0x7FFF + ((u >> 16) & 1);          // RNE to bf16
    return (short)(u >> 16);
}

// ---------------- node projection ----------------
__global__ __launch_bounds__(256)
void proj_kernel(const float* __restrict__ hsrc,
                 const float* __restrict__ Wq, const float* __restrict__ bq,
                 const float* __restrict__ Wk, const float* __restrict__ bk,
                 const float* __restrict__ Wv, const float* __restrict__ bv,
                 float* __restrict__ Q, float* __restrict__ K, float* __restrict__ V,
                 int n)
{
    const float* W;
    const float* b;
    float* out;
    if (blockIdx.y == 0)      { W = Wq; b = bq; out = Q; }
    else if (blockIdx.y == 1) { W = Wk; b = bk; out = K; }
    else                      { W = Wv; b = bv; out = V; }

    const int t    = threadIdx.x;
    const int lane = t & 63;
    const int w    = t >> 6;

    float wcol[64];
#pragma unroll
    for (int k = 0; k < 64; ++k) wcol[k] = W[k * 64 + lane];
    const float bias = b[lane];

    __shared__ float4 sh[16][16];
    const float4* __restrict__ h4 = (const float4*)hsrc;

    const int ngroups = (n + 15) >> 4;
    for (int g = blockIdx.x; g < ngroups; g += gridDim.x) {
        const int base = g << 4;
        {
            const int rs = t >> 4, c4 = t & 15;
            float4 v = make_float4(0.f, 0.f, 0.f, 0.f);
            if (base + rs < n) v = h4[(size_t)(base + rs) * 16 + c4];
            __syncthreads();
            sh[rs][c4] = v;
            __syncthreads();
        }
        float acc0 = bias, acc1 = bias, acc2 = bias, acc3 = bias;
#pragma unroll
        for (int k4 = 0; k4 < 16; ++k4) {
            const float w0 = wcol[k4 * 4 + 0], w1 = wcol[k4 * 4 + 1];
            const float w2 = wcol[k4 * 4 + 2], w3 = wcol[k4 * 4 + 3];
            const float4 a = sh[w * 4 + 0][k4];
            const float4 bb = sh[w * 4 + 1][k4];
            const float4 c = sh[w * 4 + 2][k4];
            const float4 d = sh[w * 4 + 3][k4];
            acc0 = fmaf(a.w,  w3, fmaf(a.z,  w2, fmaf(a.y,  w1, fmaf(a.x,  w0, acc0))));
            acc1 = fmaf(bb.w, w3, fmaf(bb.z, w2, fmaf(bb.y, w1, fmaf(bb.x, w0, acc1))));
            acc2 = fmaf(c.w,  w3, fmaf(c.z,  w2, fmaf(c.y,  w1, fmaf(c.x,  w0, acc2))));
            acc3 = fmaf(d.w,  w3, fmaf(d.z,  w2, fmaf(d.y,  w1, fmaf(d.x,  w0, acc3))));
        }
        const int n0 = base + w * 4;
        if (n0 + 0 < n) out[(size_t)(n0 + 0) * 64 + lane] = acc0;
        if (n0 + 1 < n) out[(size_t)(n0 + 1) * 64 + lane] = acc1;
        if (n0 + 2 < n) out[(size_t)(n0 + 2) * 64 + lane] = acc2;
        if (n0 + 3 < n) out[(size_t)(n0 + 3) * 64 + lane] = acc3;
    }
}

// ---------------- dst histogram ----------------
__global__ __launch_bounds__(256)
void hist_kernel(const int* __restrict__ dst, int* __restrict__ counts, int E)
{
    int i = blockIdx.x * 256 + threadIdx.x;
    const int stride = gridDim.x * 256;
    for (; i < E; i += stride) atomicAdd(&counts[dst[i]], 1);
}

// ---------------- exclusive scan over counts (single block, 1024 thr) ----------------
__global__ __launch_bounds__(1024)
void scan_kernel(const int* __restrict__ counts, int* __restrict__ offsets,
                 int* __restrict__ cursor, int n, int E)
{
    __shared__ int wsum[16];
    const int t = threadIdx.x;
    const int lane = t & 63;
    const int w = t >> 6;
    int carry = 0;
    for (int base = 0; base < n; base += 1024) {
        const int i = base + t;
        const int v = (i < n) ? counts[i] : 0;
        int x = v;
#pragma unroll
        for (int d = 1; d < 64; d <<= 1) {
            int y = __shfl_up(x, d);
            if (lane >= d) x += y;
        }
        if (lane == 63) wsum[w] = x;
        __syncthreads();
        if (w == 0 && lane < 16) {
            int s = wsum[lane];
#pragma unroll
            for (int d = 1; d < 16; d <<= 1) {
                int y = __shfl_up(s, d);
                if (lane >= d) s += y;
            }
            wsum[lane] = s;
        }
        __syncthreads();
        const int woff = (w == 0) ? 0 : wsum[w - 1];
        const int excl = carry + woff + (x - v);
        if (i < n) { offsets[i] = excl; cursor[i] = excl; }
        carry += wsum[15];
        __syncthreads();
    }
    if (t == 0) offsets[n] = E;
}

// ---------------- edge kernel v8: MFMA, one wave per 64-edge tile ----------------
__global__ __launch_bounds__(256)
void edge_kernel(const float* __restrict__ e,
                 const float* __restrict__ We, const float* __restrict__ be,
                 const int* __restrict__ src, const int* __restrict__ dst,
                 const float* __restrict__ Q, const float* __restrict__ K,
                 float* __restrict__ e_out,
                 float* __restrict__ s_sorted, int* __restrict__ src_sorted,
                 int* __restrict__ cursor, int E)
{
    __shared__ float tileF[4][32 * 64];             // 8 KB half-tile per wave
    const int t    = threadIdx.x;
    const int lane = t & 63;
    const int wu   = __builtin_amdgcn_readfirstlane(t >> 6);
    const int lid  = lane & 31;
    const int hi   = lane >> 5;
    float*  const myT  = tileF[wu];
    float4* const myT4 = (float4*)myT;
    const float inv = 0.35355339059327373f;         // 1/sqrt(8)

    // A fragments (We^T), loaded ONCE per wave. A[jh][ks] elem (4g+i) holds
    // We[k = 16ks + 8g + 4hi + i][j = 32jh + lid]  (m = j-row = lid).
    short8 Afr[2][4];
#pragma unroll
    for (int jh = 0; jh < 2; ++jh)
#pragma unroll
        for (int ks = 0; ks < 4; ++ks)
#pragma unroll
            for (int g = 0; g < 2; ++g)
#pragma unroll
                for (int i = 0; i < 4; ++i)
                    Afr[jh][ks][4 * g + i] =
                        f2bf(We[(16 * ks + 8 * g + 4 * hi + i) * 64 + 32 * jh + lid]);

    const int ntiles = (E + 63) >> 6;
    for (int tb = blockIdx.x * 4 + wu; tb < ntiles; tb += gridDim.x * 4) {
        const int base = tb << 6;
        const int eid  = base + lane;
        const bool valid = eid < E;
        const int eidc = valid ? eid : (E - 1);

        // claim slot for THIS lane's edge (gates stored after eh==hi phase)
        int pos = 0;
        if (valid) {
            pos = atomicAdd(&cursor[dst[eidc]], 1);
            src_sorted[pos] = src[eidc];
        }

#pragma unroll
        for (int eh = 0; eh < 2; ++eh) {
            const int erow_i = base + eh * 32 + lid;
            const int erc = erow_i < E ? erow_i : (E - 1);
            const int se = src[erc];
            const int de = dst[erc];

            // B fragments: elem (4g+i) = e[row][k = 16ks + 8g + 4hi + i]
            const float* er = e + (size_t)erc * 64 + 4 * hi;
            short8 Bfr[4];
#pragma unroll
            for (int ks = 0; ks < 4; ++ks) {
                const float4 p0 = *(const float4*)(er + 16 * ks);
                const float4 p1 = *(const float4*)(er + 16 * ks + 8);
                Bfr[ks][0] = f2bf(p0.x); Bfr[ks][1] = f2bf(p0.y);
                Bfr[ks][2] = f2bf(p0.z); Bfr[ks][3] = f2bf(p0.w);
                Bfr[ks][4] = f2bf(p1.x); Bfr[ks][5] = f2bf(p1.y);
                Bfr[ks][6] = f2bf(p1.z); Bfr[ks][7] = f2bf(p1.w);
            }

            // previous readout must be fully done before overwriting LDS
            asm volatile("s_waitcnt lgkmcnt(0)" ::: "memory");

            float gate[8];
#pragma unroll
            for (int jh = 0; jh < 2; ++jh) {
                // kv/qv gathers issued before the MFMAs of this jh
                const float* kb = K + (size_t)se * 64 + 32 * jh + 4 * hi;
                const float* qb = Q + (size_t)de * 64 + 32 * jh + 4 * hi;
                float4 kv[4], qv[4], bev[4];
#pragma unroll
                for (int hd = 0; hd < 4; ++hd) {
                    kv[hd]  = *(const float4*)(kb + 8 * hd);
                    qv[hd]  = *(const float4*)(qb + 8 * hd);
                    bev[hd] = *(const float4*)(be + 32 * jh + 8 * hd + 4 * hi);
                }

                f32x16 D = {};                    // bias added in epilogue
#pragma unroll
                for (int ks = 0; ks < 4; ++ks)
                    D = __builtin_amdgcn_mfma_f32_32x32x16_bf16(
                            Afr[jh][ks], Bfr[ks], D, 0, 0, 0);

                // epilogue: score = kv*qv*inv*(D + be); stage to LDS; head sums
#pragma unroll
                for (int hd = 0; hd < 4; ++hd) {
                    // reg r = 4*hd + i  ->  j_local = 8*hd + 4*hi + i
                    float s0 = kv[hd].x * qv[hd].x * inv * (D[4 * hd + 0] + bev[hd].x);
                    float s1 = kv[hd].y * qv[hd].y * inv * (D[4 * hd + 1] + bev[hd].y);
                    float s2 = kv[hd].z * qv[hd].z * inv * (D[4 * hd + 2] + bev[hd].z);
                    float s3 = kv[hd].w * qv[hd].w * inv * (D[4 * hd + 3] + bev[hd].w);
                    const int c4 = (8 * jh + 2 * hd + hi) ^ (lid & 15);
                    *(float4*)(myT + lid * 64 + c4 * 4) = make_float4(s0, s1, s2, s3);
                    float p = (s0 + s1) + (s2 + s3);
                    const float full = p + __shfl_xor(p, 32);
                    gate[jh * 4 + hd] = expf(fminf(fmaxf(full, -5.f), 5.f));
                }
            }

            // gates for this eh's edges live in lanes with hi == eh
            if (hi == eh && valid) {
                float4* srow = (float4*)(s_sorted + (size_t)pos * 8);
                srow[0] = make_float4(gate[0], gate[1], gate[2], gate[3]);
                srow[1] = make_float4(gate[4], gate[5], gate[6], gate[7]);
            }

            // LDS writes visible, then transposed coalesced write-out
            asm volatile("s_waitcnt lgkmcnt(0)" ::: "memory");
            float4* out4 = (float4*)e_out + (size_t)(base + eh * 32) * 16;
            const size_t limit4 = (size_t)E * 16;
            const size_t b4 = (size_t)(base + eh * 32) * 16;
#pragma unroll
            for (int it = 0; it < 8; ++it) {
                const int f  = it * 64 + lane;
                const int rr = f >> 4;
                const int mm = f & 15;
                const float4 v = myT4[rr * 16 + (mm ^ (rr & 15))];
                if (b4 + (size_t)f < limit4) out4[f] = v;
            }
        }
    }
}

// ---------------- aggregation: one wave per node, no atomics ----------------
__global__ __launch_bounds__(256)
void aggregate_kernel(const int* __restrict__ offsets,
                      const int* __restrict__ src_sorted,
                      const float* __restrict__ s_sorted,
                      const float* __restrict__ V,
                      float* __restrict__ hout, int n)
{
    const int w = (blockIdx.x * 256 + threadIdx.x) >> 6;
    const int lane = threadIdx.x & 63;
    if (w >= n) return;
    const int o0 = offsets[w], o1 = offsets[w + 1];
    const int head = lane >> 3;
    float acc = 0.f, zacc = 0.f;
    int j = o0;
    for (; j + 4 <= o1; j += 4) {
        const int sv0 = src_sorted[j + 0];
        const int sv1 = src_sorted[j + 1];
        const int sv2 = src_sorted[j + 2];
        const int sv3 = src_sorted[j + 3];
        const float s0 = s_sorted[(size_t)(j + 0) * 8 + head];
        const float s1 = s_sorted[(size_t)(j + 1) * 8 + head];
        const float s2 = s_sorted[(size_t)(j + 2) * 8 + head];
        const float s3 = s_sorted[(size_t)(j + 3) * 8 + head];
        const float v0 = V[(size_t)sv0 * 64 + lane];
        const float v1 = V[(size_t)sv1 * 64 + lane];
        const float v2 = V[(size_t)sv2 * 64 + lane];
        const float v3 = V[(size_t)sv3 * 64 + lane];
        acc = fmaf(v0, s0, acc);
        acc = fmaf(v1, s1, acc);
        acc = fmaf(v2, s2, acc);
        acc = fmaf(v3, s3, acc);
        zacc += (s0 + s1) + (s2 + s3);
    }
    for (; j < o1; ++j) {
        const int sv = src_sorted[j];
        const float s = s_sorted[(size_t)j * 8 + head];
        acc = fmaf(V[(size_t)sv * 64 + lane], s, acc);
        zacc += s;
    }
    hout[(size_t)w * 64 + lane] = acc / (zacc + 1e-6f);
}

extern "C" void kernel_launch(void* const* d_in, const int* in_sizes, int n_in,
                              void* d_out, int out_size, void* d_ws, size_t ws_size,
                              hipStream_t stream)
{
    const float* h  = (const float*)d_in[0];
    const float* e  = (const float*)d_in[1];
    const float* Wq = (const float*)d_in[2];
    const float* bq = (const float*)d_in[3];
    const float* Wk = (const float*)d_in[4];
    const float* bk = (const float*)d_in[5];
    const float* Wv = (const float*)d_in[6];
    const float* bv = (const float*)d_in[7];
    const float* We = (const float*)d_in[8];
    const float* be = (const float*)d_in[9];
    const int* src  = (const int*)d_in[10];
    const int* dst  = (const int*)d_in[11];

    const int N = in_sizes[0] / 64;
    const int E = in_sizes[1] / 64;

    float* hout  = (float*)d_out;                    // [N*64]
    float* e_out = (float*)d_out + (size_t)N * 64;   // [E*64]

    // workspace layout
    char* ws = (char*)d_ws;
    float* Q = (float*)ws;                 ws += (size_t)N * 64 * sizeof(float);
    float* K = (float*)ws;                 ws += (size_t)N * 64 * sizeof(float);
    float* V = (float*)ws;                 ws += (size_t)N * 64 * sizeof(float);
    float* s_sorted = (float*)ws;          ws += (size_t)E * 8 * sizeof(float);
    int* src_sorted = (int*)ws;            ws += (size_t)E * sizeof(int);
    int* counts  = (int*)ws;               ws += (size_t)N * sizeof(int);
    int* offsets = (int*)ws;               ws += (size_t)(N + 1) * sizeof(int);
    int* cursor  = (int*)ws;               ws += (size_t)N * sizeof(int);

    hipMemsetAsync(counts, 0, (size_t)N * sizeof(int), stream);

    // 1) Q,K,V projections
    proj_kernel<<<dim3(512, 3), dim3(256), 0, stream>>>(
        h, Wq, bq, Wk, bk, Wv, bv, Q, K, V, N);

    // 2) dst histogram
    hist_kernel<<<dim3(2048), dim3(256), 0, stream>>>(dst, counts, E);

    // 3) exclusive scan -> offsets, cursor
    scan_kernel<<<dim3(1), dim3(1024), 0, stream>>>(counts, offsets, cursor, N, E);

    // 4) edge pass: MFMA, 4 independent waves per block, grid-stride over tiles
    edge_kernel<<<dim3(1280), dim3(256), 0, stream>>>(
        e, We, be, src, dst, Q, K, e_out, s_sorted, src_sorted, cursor, E);

    // 5) aggregate per node (one wave each)
    const int ablocks = (N * 64 + 255) / 256;
    aggregate_kernel<<<dim3(ablocks), dim3(256), 0, stream>>>(
        offsets, src_sorted, s_sorted, V, hout, N);
}

// Round 9
// 608.032 us; speedup vs baseline: 2.2456x; 1.0064x over previous
//
#include <hip/hip_runtime.h>

// Graph-transformer MHA layer. N=50000, E=1600000, IN_DIM=64, H=8, D=8.
// Outputs: h_out [N*64] then e_out [E*64], fp32, concatenated in d_out.
//
// R9 (from R8's MFMA edge pass):
//  - per-(eh,jh) phase split: stage 32edges x 32j (4KB XOR-swizzled LDS) and
//    write out immediately as 128B half-rows (full cache lines, no RFO).
//    LDS 32KB -> 16KB/block.
//  - kv/qv/bev loaded just-in-time per hd in the epilogue (shorter lifetimes,
//    lower peak VGPR -> more resident waves).
//  - serial single-block scan (~100us) replaced by 3-kernel multi-block scan.

using short8 = __attribute__((ext_vector_type(8))) short;
using f32x16 = __attribute__((ext_vector_type(16))) float;

__device__ __forceinline__ short f2bf(float f) {
    unsigned u = __builtin_bit_cast(unsigned, f);
    u += 0x7FFF + ((u >> 16) & 1);          // RNE to bf16
    return (short)(u >> 16);
}

// ---------------- node projection ----------------
__global__ __launch_bounds__(256)
void proj_kernel(const float* __restrict__ hsrc,
                 const float* __restrict__ Wq, const float* __restrict__ bq,
                 const float* __restrict__ Wk, const float* __restrict__ bk,
                 const float* __restrict__ Wv, const float* __restrict__ bv,
                 float* __restrict__ Q, float* __restrict__ K, float* __restrict__ V,
                 int n)
{
    const float* W;
    const float* b;
    float* out;
    if (blockIdx.y == 0)      { W = Wq; b = bq; out = Q; }
    else if (blockIdx.y == 1) { W = Wk; b = bk; out = K; }
    else                      { W = Wv; b = bv; out = V; }

    const int t    = threadIdx.x;
    const int lane = t & 63;
    const int w    = t >> 6;

    float wcol[64];
#pragma unroll
    for (int k = 0; k < 64; ++k) wcol[k] = W[k * 64 + lane];
    const float bias = b[lane];

    __shared__ float4 sh[16][16];
    const float4* __restrict__ h4 = (const float4*)hsrc;

    const int ngroups = (n + 15) >> 4;
    for (int g = blockIdx.x; g < ngroups; g += gridDim.x) {
        const int base = g << 4;
        {
            const int rs = t >> 4, c4 = t & 15;
            float4 v = make_float4(0.f, 0.f, 0.f, 0.f);
            if (base + rs < n) v = h4[(size_t)(base + rs) * 16 + c4];
            __syncthreads();
            sh[rs][c4] = v;
            __syncthreads();
        }
        float acc0 = bias, acc1 = bias, acc2 = bias, acc3 = bias;
#pragma unroll
        for (int k4 = 0; k4 < 16; ++k4) {
            const float w0 = wcol[k4 * 4 + 0], w1 = wcol[k4 * 4 + 1];
            const float w2 = wcol[k4 * 4 + 2], w3 = wcol[k4 * 4 + 3];
            const float4 a = sh[w * 4 + 0][k4];
            const float4 bb = sh[w * 4 + 1][k4];
            const float4 c = sh[w * 4 + 2][k4];
            const float4 d = sh[w * 4 + 3][k4];
            acc0 = fmaf(a.w,  w3, fmaf(a.z,  w2, fmaf(a.y,  w1, fmaf(a.x,  w0, acc0))));
            acc1 = fmaf(bb.w, w3, fmaf(bb.z, w2, fmaf(bb.y, w1, fmaf(bb.x, w0, acc1))));
            acc2 = fmaf(c.w,  w3, fmaf(c.z,  w2, fmaf(c.y,  w1, fmaf(c.x,  w0, acc2))));
            acc3 = fmaf(d.w,  w3, fmaf(d.z,  w2, fmaf(d.y,  w1, fmaf(d.x,  w0, acc3))));
        }
        const int n0 = base + w * 4;
        if (n0 + 0 < n) out[(size_t)(n0 + 0) * 64 + lane] = acc0;
        if (n0 + 1 < n) out[(size_t)(n0 + 1) * 64 + lane] = acc1;
        if (n0 + 2 < n) out[(size_t)(n0 + 2) * 64 + lane] = acc2;
        if (n0 + 3 < n) out[(size_t)(n0 + 3) * 64 + lane] = acc3;
    }
}

// ---------------- dst histogram ----------------
__global__ __launch_bounds__(256)
void hist_kernel(const int* __restrict__ dst, int* __restrict__ counts, int E)
{
    int i = blockIdx.x * 256 + threadIdx.x;
    const int stride = gridDim.x * 256;
    for (; i < E; i += stride) atomicAdd(&counts[dst[i]], 1);
}

// ---------------- multi-block exclusive scan (3 kernels) ----------------
// scan1: per-block local exclusive scan + block total
__global__ __launch_bounds__(1024)
void scan1_kernel(const int* __restrict__ counts, int* __restrict__ offsets,
                  int* __restrict__ bsum, int n)
{
    const int t = threadIdx.x;
    const int lane = t & 63;
    const int w = t >> 6;
    __shared__ int wsum[16];
    const int i = blockIdx.x * 1024 + t;
    const int v = (i < n) ? counts[i] : 0;
    int x = v;
#pragma unroll
    for (int d = 1; d < 64; d <<= 1) {
        int y = __shfl_up(x, d);
        if (lane >= d) x += y;
    }
    if (lane == 63) wsum[w] = x;
    __syncthreads();
    if (w == 0 && lane < 16) {
        int s = wsum[lane];
#pragma unroll
        for (int d = 1; d < 16; d <<= 1) {
            int y = __shfl_up(s, d);
            if (lane >= d) s += y;
        }
        wsum[lane] = s;
    }
    __syncthreads();
    const int excl = ((w == 0) ? 0 : wsum[w - 1]) + (x - v);
    if (i < n) offsets[i] = excl;
    if (t == 1023) bsum[blockIdx.x] = excl + v;
}

// scan2: exclusive scan of block totals (single wave, nb <= 64)
__global__ __launch_bounds__(64)
void scan2_kernel(int* __restrict__ bsum, int nb)
{
    const int lane = threadIdx.x;
    const int v = (lane < nb) ? bsum[lane] : 0;
    int x = v;
#pragma unroll
    for (int d = 1; d < 64; d <<= 1) {
        int y = __shfl_up(x, d);
        if (lane >= d) x += y;
    }
    if (lane < nb) bsum[lane] = x - v;   // exclusive
}

// scan3: add block base, fill cursor, set offsets[n]
__global__ __launch_bounds__(1024)
void scan3_kernel(int* __restrict__ offsets, int* __restrict__ cursor,
                  const int* __restrict__ bsum, int n, int E)
{
    const int i = blockIdx.x * 1024 + threadIdx.x;
    if (i < n) {
        const int off = offsets[i] + bsum[blockIdx.x];
        offsets[i] = off;
        cursor[i] = off;
    }
    if (blockIdx.x == 0 && threadIdx.x == 0) offsets[n] = E;
}

// ---------------- edge kernel v9: MFMA, per-(eh,jh) staged readout ----------------
__global__ __launch_bounds__(256)
void edge_kernel(const float* __restrict__ e,
                 const float* __restrict__ We, const float* __restrict__ be,
                 const int* __restrict__ src, const int* __restrict__ dst,
                 const float* __restrict__ Q, const float* __restrict__ K,
                 float* __restrict__ e_out,
                 float* __restrict__ s_sorted, int* __restrict__ src_sorted,
                 int* __restrict__ cursor, int E)
{
    __shared__ float4 tile4[4][32 * 8];             // 4KB per wave, XOR-swizzled
    const int t    = threadIdx.x;
    const int lane = t & 63;
    const int wu   = __builtin_amdgcn_readfirstlane(t >> 6);
    const int lid  = lane & 31;
    const int hi   = lane >> 5;
    float4* const myT4 = tile4[wu];
    const float inv = 0.35355339059327373f;         // 1/sqrt(8)

    // A fragments (We^T), loaded once per wave. A[jh][ks] elem (4g+i) holds
    // We[k = 16ks + 8g + 4hi + i][j = 32jh + lid].
    short8 Afr[2][4];
#pragma unroll
    for (int jh = 0; jh < 2; ++jh)
#pragma unroll
        for (int ks = 0; ks < 4; ++ks)
#pragma unroll
            for (int g = 0; g < 2; ++g)
#pragma unroll
                for (int i = 0; i < 4; ++i)
                    Afr[jh][ks][4 * g + i] =
                        f2bf(We[(16 * ks + 8 * g + 4 * hi + i) * 64 + 32 * jh + lid]);

    const int ntiles = (E + 63) >> 6;
    for (int tb = blockIdx.x * 4 + wu; tb < ntiles; tb += gridDim.x * 4) {
        const int base = tb << 6;
        const int eid  = base + lane;
        const bool valid = eid < E;
        const int eidc = valid ? eid : (E - 1);

        // claim slot for this lane's edge
        int pos = 0;
        if (valid) {
            pos = atomicAdd(&cursor[dst[eidc]], 1);
            src_sorted[pos] = src[eidc];
        }

#pragma unroll
        for (int eh = 0; eh < 2; ++eh) {
            const int erow_i = base + eh * 32 + lid;
            const int erc = erow_i < E ? erow_i : (E - 1);
            const int se = src[erc];
            const int de = dst[erc];

            // B fragments: elem (4g+i) = e[row][k = 16ks + 8g + 4hi + i]
            const float* er = e + (size_t)erc * 64 + 4 * hi;
            short8 Bfr[4];
#pragma unroll
            for (int ks = 0; ks < 4; ++ks) {
                const float4 p0 = *(const float4*)(er + 16 * ks);
                const float4 p1 = *(const float4*)(er + 16 * ks + 8);
                Bfr[ks][0] = f2bf(p0.x); Bfr[ks][1] = f2bf(p0.y);
                Bfr[ks][2] = f2bf(p0.z); Bfr[ks][3] = f2bf(p0.w);
                Bfr[ks][4] = f2bf(p1.x); Bfr[ks][5] = f2bf(p1.y);
                Bfr[ks][6] = f2bf(p1.z); Bfr[ks][7] = f2bf(p1.w);
            }

            float gate[8];
#pragma unroll
            for (int jh = 0; jh < 2; ++jh) {
                f32x16 D = {};
#pragma unroll
                for (int ks = 0; ks < 4; ++ks)
                    D = __builtin_amdgcn_mfma_f32_32x32x16_bf16(
                            Afr[jh][ks], Bfr[ks], D, 0, 0, 0);

                // previous phase's LDS reads must be done before overwrite
                asm volatile("s_waitcnt lgkmcnt(0)" ::: "memory");

                // epilogue: JIT kv/qv/bev loads per hd; stage + head sums
                const float* kb = K + (size_t)se * 64 + 32 * jh + 4 * hi;
                const float* qb = Q + (size_t)de * 64 + 32 * jh + 4 * hi;
#pragma unroll
                for (int hd = 0; hd < 4; ++hd) {
                    const float4 kv  = *(const float4*)(kb + 8 * hd);
                    const float4 qv  = *(const float4*)(qb + 8 * hd);
                    const float4 bev = *(const float4*)(be + 32 * jh + 8 * hd + 4 * hi);
                    // reg r = 4*hd + i  ->  j_local(within jh) = 8*hd + 4*hi + i
                    const float s0 = kv.x * qv.x * inv * (D[4 * hd + 0] + bev.x);
                    const float s1 = kv.y * qv.y * inv * (D[4 * hd + 1] + bev.y);
                    const float s2 = kv.z * qv.z * inv * (D[4 * hd + 2] + bev.z);
                    const float s3 = kv.w * qv.w * inv * (D[4 * hd + 3] + bev.w);
                    const int c4 = (2 * hd + hi) ^ (lid & 7);       // XOR swizzle
                    myT4[lid * 8 + c4] = make_float4(s0, s1, s2, s3);
                    float p = (s0 + s1) + (s2 + s3);
                    const float full = p + __shfl_xor(p, 32);
                    gate[jh * 4 + hd] = expf(fminf(fmaxf(full, -5.f), 5.f));
                }

                // readout: 4 x 64-lane dwordx4 stores of 128B half-rows
                // lane l: r8 = l>>3 (row group), m = l&7 (float4 col)
                const int r8 = lane >> 3, m = lane & 7;
#pragma unroll
                for (int it = 0; it < 4; ++it) {
                    const int row = it * 8 + r8;                    // edge row 0..31
                    const int edge2 = base + eh * 32 + row;
                    const float4 v = myT4[row * 8 + (m ^ (row & 7))];
                    if (edge2 < E)
                        *((float4*)e_out + (size_t)edge2 * 16 + jh * 8 + m) = v;
                }
            }

            // gates for this eh's edges live in lanes with hi == eh
            if (hi == eh && valid) {
                float4* srow = (float4*)(s_sorted + (size_t)pos * 8);
                srow[0] = make_float4(gate[0], gate[1], gate[2], gate[3]);
                srow[1] = make_float4(gate[4], gate[5], gate[6], gate[7]);
            }
        }
    }
}

// ---------------- aggregation: one wave per node, no atomics ----------------
__global__ __launch_bounds__(256)
void aggregate_kernel(const int* __restrict__ offsets,
                      const int* __restrict__ src_sorted,
                      const float* __restrict__ s_sorted,
                      const float* __restrict__ V,
                      float* __restrict__ hout, int n)
{
    const int w = (blockIdx.x * 256 + threadIdx.x) >> 6;
    const int lane = threadIdx.x & 63;
    if (w >= n) return;
    const int o0 = offsets[w], o1 = offsets[w + 1];
    const int head = lane >> 3;
    float acc = 0.f, zacc = 0.f;
    int j = o0;
    for (; j + 4 <= o1; j += 4) {
        const int sv0 = src_sorted[j + 0];
        const int sv1 = src_sorted[j + 1];
        const int sv2 = src_sorted[j + 2];
        const int sv3 = src_sorted[j + 3];
        const float s0 = s_sorted[(size_t)(j + 0) * 8 + head];
        const float s1 = s_sorted[(size_t)(j + 1) * 8 + head];
        const float s2 = s_sorted[(size_t)(j + 2) * 8 + head];
        const float s3 = s_sorted[(size_t)(j + 3) * 8 + head];
        const float v0 = V[(size_t)sv0 * 64 + lane];
        const float v1 = V[(size_t)sv1 * 64 + lane];
        const float v2 = V[(size_t)sv2 * 64 + lane];
        const float v3 = V[(size_t)sv3 * 64 + lane];
        acc = fmaf(v0, s0, acc);
        acc = fmaf(v1, s1, acc);
        acc = fmaf(v2, s2, acc);
        acc = fmaf(v3, s3, acc);
        zacc += (s0 + s1) + (s2 + s3);
    }
    for (; j < o1; ++j) {
        const int sv = src_sorted[j];
        const float s = s_sorted[(size_t)j * 8 + head];
        acc = fmaf(V[(size_t)sv * 64 + lane], s, acc);
        zacc += s;
    }
    hout[(size_t)w * 64 + lane] = acc / (zacc + 1e-6f);
}

extern "C" void kernel_launch(void* const* d_in, const int* in_sizes, int n_in,
                              void* d_out, int out_size, void* d_ws, size_t ws_size,
                              hipStream_t stream)
{
    const float* h  = (const float*)d_in[0];
    const float* e  = (const float*)d_in[1];
    const float* Wq = (const float*)d_in[2];
    const float* bq = (const float*)d_in[3];
    const float* Wk = (const float*)d_in[4];
    const float* bk = (const float*)d_in[5];
    const float* Wv = (const float*)d_in[6];
    const float* bv = (const float*)d_in[7];
    const float* We = (const float*)d_in[8];
    const float* be = (const float*)d_in[9];
    const int* src  = (const int*)d_in[10];
    const int* dst  = (const int*)d_in[11];

    const int N = in_sizes[0] / 64;
    const int E = in_sizes[1] / 64;

    float* hout  = (float*)d_out;                    // [N*64]
    float* e_out = (float*)d_out + (size_t)N * 64;   // [E*64]

    // workspace layout
    char* ws = (char*)d_ws;
    float* Q = (float*)ws;                 ws += (size_t)N * 64 * sizeof(float);
    float* K = (float*)ws;                 ws += (size_t)N * 64 * sizeof(float);
    float* V = (float*)ws;                 ws += (size_t)N * 64 * sizeof(float);
    float* s_sorted = (float*)ws;          ws += (size_t)E * 8 * sizeof(float);
    int* src_sorted = (int*)ws;            ws += (size_t)E * sizeof(int);
    int* counts  = (int*)ws;               ws += (size_t)N * sizeof(int);
    int* offsets = (int*)ws;               ws += (size_t)(N + 1) * sizeof(int);
    int* cursor  = (int*)ws;               ws += (size_t)N * sizeof(int);
    int* bsum    = (int*)ws;               ws += 64 * sizeof(int);

    hipMemsetAsync(counts, 0, (size_t)N * sizeof(int), stream);

    // 1) Q,K,V projections
    proj_kernel<<<dim3(512, 3), dim3(256), 0, stream>>>(
        h, Wq, bq, Wk, bk, Wv, bv, Q, K, V, N);

    // 2) dst histogram
    hist_kernel<<<dim3(2048), dim3(256), 0, stream>>>(dst, counts, E);

    // 3) exclusive scan -> offsets, cursor (multi-block, 3 kernels)
    const int nb = (N + 1023) / 1024;
    scan1_kernel<<<dim3(nb), dim3(1024), 0, stream>>>(counts, offsets, bsum, N);
    scan2_kernel<<<dim3(1), dim3(64), 0, stream>>>(bsum, nb);
    scan3_kernel<<<dim3(nb), dim3(1024), 0, stream>>>(offsets, cursor, bsum, N, E);

    // 4) edge pass: MFMA, 4 independent waves per block, grid-stride over tiles
    edge_kernel<<<dim3(2560), dim3(256), 0, stream>>>(
        e, We, be, src, dst, Q, K, e_out, s_sorted, src_sorted, cursor, E);

    // 5) aggregate per node (one wave each)
    const int ablocks = (N * 64 + 255) / 256;
    aggregate_kernel<<<dim3(ablocks), dim3(256), 0, stream>>>(
        offsets, src_sorted, s_sorted, V, hout, N);
}